// Round 4
// baseline (2087.346 us; speedup 1.0000x reference)
//
#include <hip/hip_runtime.h>
#include <cstdint>
#include <cstddef>

// Problem dims (fixed by setup_inputs)
#define T_DIM 8192
#define H_DIM 4096
#define I_DIM 11008

// Tile geometry: 128x128 block tile, BK=64, 256 threads = 4 waves (2x2),
// each wave owns a 64x64 sub-tile = 4x4 MFMAs of 16x16x64 i8.
// Packed operand layout (both A and B operands): for each [128 rows x 64 k]
// tile, element (row, k) lives at byte offset
//   R*1024 + lane*16 + j   where R = row/16, m = row%16, g = k/16, j = k%16,
//   lane = g*16 + m
// so MFMA lane l reads its 16B fragment at R*1024 + l*16 (conflict-free
// ds_read_b128), and global_load_lds (wave-uniform base + lane*16) stages it
// with zero address shuffling.
//
// R3 (kept): XCD-chunked block remap -> FETCH 2.9 GB -> 0.63 GB, weights
// served from XCD L2. R4: now that the kernel is latency-bound (0.92 TB/s,
// MfmaUtil 43.5%), add the counted-vmcnt triple-buffer pipeline (R2's
// refcheck-proven loop) ON TOP of the remap: per K-step the vmcnt wait is
// counted (6 gateup / 4 down), never 0 in steady state, so loads span the
// compute phase and the ~1450 cy/step latency hole closes.

typedef int v4i __attribute__((ext_vector_type(4)));

__device__ __forceinline__ void async16(const void* g, void* l) {
    __builtin_amdgcn_global_load_lds(
        (const __attribute__((address_space(1))) unsigned int*)g,
        (__attribute__((address_space(3))) unsigned int*)l,
        16, 0, 0);
}

// Block-id remap: HW dispatch id D -> (bm, bn).
// NBLK must be divisible by 8. NBN = #bn columns, 64 bm rows always.
__device__ __forceinline__ void remap_tile(int D, int NBLK, int NBN,
                                           int& bm, int& bn) {
    // XCD round-robin -> contiguous logical chunks per XCD.
    const int L = (D & 7) * (NBLK >> 3) + (D >> 3);
    // Groups of 4 bn-columns, bm-inner within the group.
    const int grp = L >> 8;              // / (64*4)
    const int r = L & 255;
    const int gbase = grp * 4;
    const int gcols = (NBN - gbase < 4) ? (NBN - gbase) : 4;
    bn = gbase + r % gcols;
    bm = r / gcols;
}

// ---------------- pack kernels ----------------

// Quantize fp32 x -> int8, write in packed tile layout.
// grid: (T/128)*(H/64) = 64*64 = 4096 blocks, 256 threads.
__global__ void quant_pack_x(const float* __restrict__ x,
                             const float* __restrict__ scale_p,
                             int8_t* __restrict__ qx) {
    const float s = scale_p[0];
    const int tile = blockIdx.x;
    const int tm = tile >> 6;     // H/64 == 64 tiles in k
    const int tk = tile & 63;
    int8_t* dst = qx + (size_t)tile * 8192;
#pragma unroll
    for (int pass = 0; pass < 2; ++pass) {
        const int slot = threadIdx.x + pass * 256;   // 0..511
        const int m = slot & 15;
        const int g = (slot >> 4) & 3;
        const int R = slot >> 6;
        const int row = tm * 128 + R * 16 + m;
        const int col = tk * 64 + g * 16;
        const float4* src = (const float4*)(x + (size_t)row * H_DIM + col);
        union { int8_t b[16]; v4i v; } tmp;
#pragma unroll
        for (int q4 = 0; q4 < 4; ++q4) {
            float4 v = src[q4];
            tmp.b[q4 * 4 + 0] = (int8_t)fminf(fmaxf(rintf(v.x / s), -127.f), 127.f);
            tmp.b[q4 * 4 + 1] = (int8_t)fminf(fmaxf(rintf(v.y / s), -127.f), 127.f);
            tmp.b[q4 * 4 + 2] = (int8_t)fminf(fmaxf(rintf(v.z / s), -127.f), 127.f);
            tmp.b[q4 * 4 + 3] = (int8_t)fminf(fmaxf(rintf(v.w / s), -127.f), 127.f);
        }
        *(v4i*)(dst + slot * 16) = tmp.v;
    }
}

// int32 weights -> int8, packed tile layout. rows%128==0, cols%64==0.
// grid: (rows/128)*(cols/64) blocks, 256 threads.
__global__ void pack_w(const int* __restrict__ w, int8_t* __restrict__ w8,
                       int cols) {
    const int tiles_k = cols >> 6;
    const int tile = blockIdx.x;
    const int tm = tile / tiles_k;
    const int tk = tile - tm * tiles_k;
    int8_t* dst = w8 + (size_t)tile * 8192;
#pragma unroll
    for (int pass = 0; pass < 2; ++pass) {
        const int slot = threadIdx.x + pass * 256;
        const int m = slot & 15;
        const int g = (slot >> 4) & 3;
        const int R = slot >> 6;
        const int4* src = (const int4*)(w + (size_t)(tm * 128 + R * 16 + m) * cols
                                          + tk * 64 + g * 16);
        union { int8_t b[16]; v4i v; } tmp;
#pragma unroll
        for (int q4 = 0; q4 < 4; ++q4) {
            int4 v = src[q4];
            tmp.b[q4 * 4 + 0] = (int8_t)v.x;
            tmp.b[q4 * 4 + 1] = (int8_t)v.y;
            tmp.b[q4 * 4 + 2] = (int8_t)v.z;
            tmp.b[q4 * 4 + 3] = (int8_t)v.w;
        }
        *(v4i*)(dst + slot * 16) = tmp.v;
    }
}

// ---------------- fused gate/up GEMM + SwiGLU + requant ----------------
// grid: 1D, (I/128)*(T/128) = 86*64 = 5504 blocks, 256 threads.
__global__ __launch_bounds__(256, 2)
void gateup_gemm(const int8_t* __restrict__ qx,
                 const int8_t* __restrict__ wg8,
                 const int8_t* __restrict__ wu8,
                 const float* __restrict__ ws_gate,
                 const float* __restrict__ ws_up,
                 const float* __restrict__ b_gate,
                 const float* __restrict__ b_up,
                 const float* __restrict__ asg_p,
                 const float* __restrict__ asd_p,
                 int8_t* __restrict__ qh) {
    // Triple-buffered: 3 x 8KB per operand = 72 KB total (2 blocks/CU).
    __shared__ __align__(16) int8_t lA [3][8192];
    __shared__ __align__(16) int8_t lBg[3][8192];
    __shared__ __align__(16) int8_t lBu[3][8192];

    const int tid = threadIdx.x;
    const int lane = tid & 63;
    const int w = tid >> 6;
    const int wm = w >> 1, wn = w & 1;

    int bm, bn;
    remap_tile(blockIdx.x, (I_DIM / 128) * (T_DIM / 128), I_DIM / 128, bm, bn);

    const int soff = (w * 64 + lane) * 16;   // per-lane staging offset
    const int8_t* At = qx  + (size_t)bm * (H_DIM / 64) * 8192 + soff;
    const int8_t* Bg = wg8 + (size_t)bn * (H_DIM / 64) * 8192 + soff;
    const int8_t* Bu = wu8 + (size_t)bn * (H_DIM / 64) * 8192 + soff;

    v4i accg[4][4] = {};
    v4i accu[4][4] = {};

    const int ldst = w * 1024;               // wave-uniform LDS dest

    // Prologue: stage K-tiles 0 and 1 into buffers 0 and 1.
    // 12 loads in flight per wave; no drain here.
    async16(At,        &lA [0][ldst]);
    async16(At + 4096, &lA [0][ldst + 4096]);
    async16(Bg,        &lBg[0][ldst]);
    async16(Bg + 4096, &lBg[0][ldst + 4096]);
    async16(Bu,        &lBu[0][ldst]);
    async16(Bu + 4096, &lBu[0][ldst + 4096]);
    async16(At + 8192,        &lA [1][ldst]);
    async16(At + 8192 + 4096, &lA [1][ldst + 4096]);
    async16(Bg + 8192,        &lBg[1][ldst]);
    async16(Bg + 8192 + 4096, &lBg[1][ldst + 4096]);
    async16(Bu + 8192,        &lBu[1][ldst]);
    async16(Bu + 8192 + 4096, &lBu[1][ldst + 4096]);

    const int NT = H_DIM / 64;   // 64
    int cur = 0;
    for (int kk = 0; kk < NT; ++kk) {
        // Counted wait: tile kk's 6 loads are the oldest; allow tile kk+1's
        // 6 to stay in flight. Only the last iteration drains to 0.
        if (kk == NT - 1) {
            asm volatile("s_waitcnt vmcnt(0)" ::: "memory");
        } else {
            asm volatile("s_waitcnt vmcnt(6)" ::: "memory");
        }
        // Barrier: (a) all waves' tile-kk loads landed -> LDS[cur] complete;
        // (b) all waves consumed tile kk-1 -> buf[(kk+2)%3] is free to write.
        __builtin_amdgcn_s_barrier();

        if (kk + 2 < NT) {
            const int pb = (cur >= 1) ? cur - 1 : cur + 2;   // (cur+2)%3
            const size_t off = (size_t)(kk + 2) * 8192;
            async16(At + off,        &lA [pb][ldst]);
            async16(At + off + 4096, &lA [pb][ldst + 4096]);
            async16(Bg + off,        &lBg[pb][ldst]);
            async16(Bg + off + 4096, &lBg[pb][ldst + 4096]);
            async16(Bu + off,        &lBu[pb][ldst]);
            async16(Bu + off + 4096, &lBu[pb][ldst + 4096]);
        }

        v4i af[4], bgf[4], buf2[4];
#pragma unroll
        for (int mt = 0; mt < 4; ++mt)
            af[mt] = *(const v4i*)(&lA[cur][((wm * 4 + mt) * 64 + lane) * 16]);
#pragma unroll
        for (int nt = 0; nt < 4; ++nt) {
            bgf[nt]  = *(const v4i*)(&lBg[cur][((wn * 4 + nt) * 64 + lane) * 16]);
            buf2[nt] = *(const v4i*)(&lBu[cur][((wn * 4 + nt) * 64 + lane) * 16]);
        }
#pragma unroll
        for (int mt = 0; mt < 4; ++mt)
#pragma unroll
            for (int nt = 0; nt < 4; ++nt) {
                accg[mt][nt] = __builtin_amdgcn_mfma_i32_16x16x64_i8(
                    af[mt], bgf[nt], accg[mt][nt], 0, 0, 0);
                accu[mt][nt] = __builtin_amdgcn_mfma_i32_16x16x64_i8(
                    af[mt], buf2[nt], accu[mt][nt], 0, 0, 0);
            }

        cur = (cur == 2) ? 0 : cur + 1;
    }

    // Epilogue: dequant, silu(gate)*up, requant -> qh in packed-A layout.
    const float sg = asg_p[0];
    const float sd = asd_p[0];
    const int jc = lane & 15, lg = lane >> 4;
    const size_t tile_base =
        ((size_t)bm * (I_DIM / 64) + (size_t)bn * 2 + wn) * 8192;
#pragma unroll
    for (int nt = 0; nt < 4; ++nt) {
        const int col = bn * 128 + wn * 64 + nt * 16 + jc;
        const float wsg = sg * ws_gate[col];
        const float wsu = sg * ws_up[col];
        const float bgv = b_gate[col];
        const float buv = b_up[col];
#pragma unroll
        for (int mt = 0; mt < 4; ++mt) {
            const size_t base = tile_base
                + (size_t)((((wm * 4 + mt) * 64) + nt * 16 + lg * 4) * 16 + jc);
#pragma unroll
            for (int r = 0; r < 4; ++r) {
                const float gate = (float)accg[mt][nt][r] * wsg + bgv;
                const float up   = (float)accu[mt][nt][r] * wsu + buv;
                const float hv = (gate / (1.0f + expf(-gate))) * up;
                const float qv = fminf(fmaxf(rintf(hv / sd), -127.f), 127.f);
                qh[base + (size_t)r * 16] = (int8_t)qv;
            }
        }
    }
}

// ---------------- down GEMM + dequant ----------------
// grid: 1D, (H/128)*(T/128) = 32*64 = 2048 blocks, 256 threads.
__global__ __launch_bounds__(256, 2)
void down_gemm(const int8_t* __restrict__ qh,
               const int8_t* __restrict__ wd8,
               const float* __restrict__ ws_down,
               const float* __restrict__ b_down,
               const float* __restrict__ asd_p,
               float* __restrict__ out) {
    __shared__ __align__(16) int8_t lA[3][8192];
    __shared__ __align__(16) int8_t lB[3][8192];

    const int tid = threadIdx.x;
    const int lane = tid & 63;
    const int w = tid >> 6;
    const int wm = w >> 1, wn = w & 1;

    int bm, bn;
    remap_tile(blockIdx.x, (H_DIM / 128) * (T_DIM / 128), H_DIM / 128, bm, bn);

    const int soff = (w * 64 + lane) * 16;
    const int8_t* At = qh  + (size_t)bm * (I_DIM / 64) * 8192 + soff;
    const int8_t* Bt = wd8 + (size_t)bn * (I_DIM / 64) * 8192 + soff;

    v4i acc[4][4] = {};

    const int ldst = w * 1024;

    // Prologue: stage K-tiles 0 and 1. 8 loads in flight per wave.
    async16(At,        &lA[0][ldst]);
    async16(At + 4096, &lA[0][ldst + 4096]);
    async16(Bt,        &lB[0][ldst]);
    async16(Bt + 4096, &lB[0][ldst + 4096]);
    async16(At + 8192,        &lA[1][ldst]);
    async16(At + 8192 + 4096, &lA[1][ldst + 4096]);
    async16(Bt + 8192,        &lB[1][ldst]);
    async16(Bt + 8192 + 4096, &lB[1][ldst + 4096]);

    const int NT = I_DIM / 64;   // 172
    int cur = 0;
    for (int kk = 0; kk < NT; ++kk) {
        if (kk == NT - 1) {
            asm volatile("s_waitcnt vmcnt(0)" ::: "memory");
        } else {
            asm volatile("s_waitcnt vmcnt(4)" ::: "memory");
        }
        __builtin_amdgcn_s_barrier();

        if (kk + 2 < NT) {
            const int pb = (cur >= 1) ? cur - 1 : cur + 2;   // (cur+2)%3
            const size_t off = (size_t)(kk + 2) * 8192;
            async16(At + off,        &lA[pb][ldst]);
            async16(At + off + 4096, &lA[pb][ldst + 4096]);
            async16(Bt + off,        &lB[pb][ldst]);
            async16(Bt + off + 4096, &lB[pb][ldst + 4096]);
        }

        v4i af[4], bf[4];
#pragma unroll
        for (int mt = 0; mt < 4; ++mt)
            af[mt] = *(const v4i*)(&lA[cur][((wm * 4 + mt) * 64 + lane) * 16]);
#pragma unroll
        for (int nt = 0; nt < 4; ++nt)
            bf[nt] = *(const v4i*)(&lB[cur][((wn * 4 + nt) * 64 + lane) * 16]);
#pragma unroll
        for (int mt = 0; mt < 4; ++mt)
#pragma unroll
            for (int nt = 0; nt < 4; ++nt)
                acc[mt][nt] = __builtin_amdgcn_mfma_i32_16x16x64_i8(
                    af[mt], bf[nt], acc[mt][nt], 0, 0, 0);

        cur = (cur == 2) ? 0 : cur + 1;
    }

    const float sd = asd_p[0];
    const int jc = lane & 15, lg = lane >> 4;
#pragma unroll
    for (int nt = 0; nt < 4; ++nt) {
        const int hcol = bn * 128 + wn * 64 + nt * 16 + jc;
        const float sc = sd * ws_down[hcol];
        const float bv = b_down[hcol];
#pragma unroll
        for (int mt = 0; mt < 4; ++mt) {
            const int trow0 = bm * 128 + wm * 64 + mt * 16 + lg * 4;
#pragma unroll
            for (int r = 0; r < 4; ++r)
                out[(size_t)(trow0 + r) * H_DIM + hcol] =
                    (float)acc[mt][nt][r] * sc + bv;
        }
    }
}

// ---------------- launch ----------------

extern "C" void kernel_launch(void* const* d_in, const int* in_sizes, int n_in,
                              void* d_out, int out_size, void* d_ws, size_t ws_size,
                              hipStream_t stream) {
    const float* x       = (const float*)d_in[0];
    const int*   w_gate  = (const int*)d_in[1];
    const int*   w_up    = (const int*)d_in[2];
    const int*   w_down  = (const int*)d_in[3];
    const float* ws_gate = (const float*)d_in[4];
    const float* ws_up   = (const float*)d_in[5];
    const float* ws_down = (const float*)d_in[6];
    const float* b_gate  = (const float*)d_in[7];
    const float* b_up    = (const float*)d_in[8];
    const float* b_down  = (const float*)d_in[9];
    const float* asg     = (const float*)d_in[10];
    const float* asd     = (const float*)d_in[11];
    float* out = (float*)d_out;

    int8_t* ws8 = (int8_t*)d_ws;
    int8_t* qx  = ws8;                       // 33,554,432 B
    int8_t* qh  = ws8 + 33554432;            // 90,177,536 B
    int8_t* wg8 = ws8 + 123731968;           // 45,088,768 B
    int8_t* wu8 = ws8 + 168820736;           // 45,088,768 B (end 213,909,504)
    int8_t* wd8 = wg8;                       // reused after gateup_gemm

    quant_pack_x<<<dim3(4096), dim3(256), 0, stream>>>(x, asg, qx);
    pack_w<<<dim3(5504), dim3(256), 0, stream>>>(w_gate, wg8, H_DIM);
    pack_w<<<dim3(5504), dim3(256), 0, stream>>>(w_up,   wu8, H_DIM);
    gateup_gemm<<<dim3(5504), dim3(256), 0, stream>>>(
        qx, wg8, wu8, ws_gate, ws_up, b_gate, b_up, asg, asd, qh);
    pack_w<<<dim3(5504), dim3(256), 0, stream>>>(w_down, wd8, I_DIM);
    down_gemm<<<dim3(2048), dim3(256), 0, stream>>>(
        qh, wd8, ws_down, b_down, asd, out);
}

// Round 5
// 1591.735 us; speedup vs baseline: 1.3114x; 1.3114x over previous
//
#include <hip/hip_runtime.h>
#include <cstdint>
#include <cstddef>

// Problem dims (fixed by setup_inputs)
#define T_DIM 8192
#define H_DIM 4096
#define I_DIM 11008

// Tile geometry: 128x128 block tile, BK=128, 256 threads = 4 waves (2x2),
// each wave owns a 64x64 sub-tile = 4x4 MFMAs of 16x16x64 i8, 2 k-slices.
// Packed operand layout (both A and B operands): for each [128 rows x 64 k]
// tile, element (row, k) lives at byte offset
//   R*1024 + lane*16 + j   where R = row/16, m = row%16, g = k/16, j = k%16,
//   lane = g*16 + m
// so MFMA lane l reads its 16B fragment at R*1024 + l*16 (conflict-free
// ds_read_b128), and global_load_lds (wave-uniform base + lane*16) stages it
// with zero address shuffling. A BK=128 step = 2 consecutive packed tiles.
//
// History: R3 remap (FETCH 2.9->0.63 GB) kept. R1/R2/R4 pipelining attempts
// all regressed ~40% (3 A/Bs: DMA-to-LDS writes contend with ds_reads when
// overlapped with compute; serial 2-barrier structure + 2-block anti-phase
// is the winning overlap mechanism). R5: amortize the per-step hole
// (~680 cy fixed latency+barrier cost) over 2x MFMA work: BK 64 -> 128.
// Hole count halves (64->32 steps gateup, 172->86 down).

typedef int v4i __attribute__((ext_vector_type(4)));

__device__ __forceinline__ void async16(const void* g, void* l) {
    __builtin_amdgcn_global_load_lds(
        (const __attribute__((address_space(1))) unsigned int*)g,
        (__attribute__((address_space(3))) unsigned int*)l,
        16, 0, 0);
}

// Block-id remap: HW dispatch id D -> (bm, bn).
// NBLK must be divisible by 8. NBN = #bn columns, 64 bm rows always.
__device__ __forceinline__ void remap_tile(int D, int NBLK, int NBN,
                                           int& bm, int& bn) {
    // XCD round-robin -> contiguous logical chunks per XCD.
    const int L = (D & 7) * (NBLK >> 3) + (D >> 3);
    // Groups of 4 bn-columns, bm-inner within the group.
    const int grp = L >> 8;              // / (64*4)
    const int r = L & 255;
    const int gbase = grp * 4;
    const int gcols = (NBN - gbase < 4) ? (NBN - gbase) : 4;
    bn = gbase + r % gcols;
    bm = r / gcols;
}

// ---------------- pack kernels ----------------

// Quantize fp32 x -> int8, write in packed tile layout.
// grid: (T/128)*(H/64) = 64*64 = 4096 blocks, 256 threads.
__global__ void quant_pack_x(const float* __restrict__ x,
                             const float* __restrict__ scale_p,
                             int8_t* __restrict__ qx) {
    const float s = scale_p[0];
    const int tile = blockIdx.x;
    const int tm = tile >> 6;     // H/64 == 64 tiles in k
    const int tk = tile & 63;
    int8_t* dst = qx + (size_t)tile * 8192;
#pragma unroll
    for (int pass = 0; pass < 2; ++pass) {
        const int slot = threadIdx.x + pass * 256;   // 0..511
        const int m = slot & 15;
        const int g = (slot >> 4) & 3;
        const int R = slot >> 6;
        const int row = tm * 128 + R * 16 + m;
        const int col = tk * 64 + g * 16;
        const float4* src = (const float4*)(x + (size_t)row * H_DIM + col);
        union { int8_t b[16]; v4i v; } tmp;
#pragma unroll
        for (int q4 = 0; q4 < 4; ++q4) {
            float4 v = src[q4];
            tmp.b[q4 * 4 + 0] = (int8_t)fminf(fmaxf(rintf(v.x / s), -127.f), 127.f);
            tmp.b[q4 * 4 + 1] = (int8_t)fminf(fmaxf(rintf(v.y / s), -127.f), 127.f);
            tmp.b[q4 * 4 + 2] = (int8_t)fminf(fmaxf(rintf(v.z / s), -127.f), 127.f);
            tmp.b[q4 * 4 + 3] = (int8_t)fminf(fmaxf(rintf(v.w / s), -127.f), 127.f);
        }
        *(v4i*)(dst + slot * 16) = tmp.v;
    }
}

// int32 weights -> int8, packed tile layout. rows%128==0, cols%64==0.
// grid: (rows/128)*(cols/64) blocks, 256 threads.
__global__ void pack_w(const int* __restrict__ w, int8_t* __restrict__ w8,
                       int cols) {
    const int tiles_k = cols >> 6;
    const int tile = blockIdx.x;
    const int tm = tile / tiles_k;
    const int tk = tile - tm * tiles_k;
    int8_t* dst = w8 + (size_t)tile * 8192;
#pragma unroll
    for (int pass = 0; pass < 2; ++pass) {
        const int slot = threadIdx.x + pass * 256;
        const int m = slot & 15;
        const int g = (slot >> 4) & 3;
        const int R = slot >> 6;
        const int4* src = (const int4*)(w + (size_t)(tm * 128 + R * 16 + m) * cols
                                          + tk * 64 + g * 16);
        union { int8_t b[16]; v4i v; } tmp;
#pragma unroll
        for (int q4 = 0; q4 < 4; ++q4) {
            int4 v = src[q4];
            tmp.b[q4 * 4 + 0] = (int8_t)v.x;
            tmp.b[q4 * 4 + 1] = (int8_t)v.y;
            tmp.b[q4 * 4 + 2] = (int8_t)v.z;
            tmp.b[q4 * 4 + 3] = (int8_t)v.w;
        }
        *(v4i*)(dst + slot * 16) = tmp.v;
    }
}

// ---------------- fused gate/up GEMM + SwiGLU + requant ----------------
// grid: 1D, (I/128)*(T/128) = 86*64 = 5504 blocks, 256 threads.
__global__ __launch_bounds__(256, 2)
void gateup_gemm(const int8_t* __restrict__ qx,
                 const int8_t* __restrict__ wg8,
                 const int8_t* __restrict__ wu8,
                 const float* __restrict__ ws_gate,
                 const float* __restrict__ ws_up,
                 const float* __restrict__ b_gate,
                 const float* __restrict__ b_up,
                 const float* __restrict__ asg_p,
                 const float* __restrict__ asd_p,
                 int8_t* __restrict__ qh) {
    // BK=128: 16 KB per operand (2 packed 8KB k-tiles back-to-back).
    __shared__ __align__(16) int8_t lA [16384];
    __shared__ __align__(16) int8_t lBg[16384];
    __shared__ __align__(16) int8_t lBu[16384];

    const int tid = threadIdx.x;
    const int lane = tid & 63;
    const int w = tid >> 6;
    const int wm = w >> 1, wn = w & 1;

    int bm, bn;
    remap_tile(blockIdx.x, (I_DIM / 128) * (T_DIM / 128), I_DIM / 128, bm, bn);

    const int8_t* At = qx  + (size_t)bm * (H_DIM / 64) * 8192;
    const int8_t* Bg = wg8 + (size_t)bn * (H_DIM / 64) * 8192;
    const int8_t* Bu = wu8 + (size_t)bn * (H_DIM / 64) * 8192;

    v4i accg[4][4] = {};
    v4i accu[4][4] = {};

    const int soff = (w * 64 + lane) * 16;   // per-lane staging offset
    int8_t* lA_w  = lA  + w * 1024;          // wave-uniform LDS dest
    int8_t* lBg_w = lBg + w * 1024;
    int8_t* lBu_w = lBu + w * 1024;

    for (int kk = 0; kk < H_DIM / 128; ++kk) {   // 32 steps
        __syncthreads();
        const int8_t* a  = At + (size_t)kk * 16384 + soff;
        const int8_t* g_ = Bg + (size_t)kk * 16384 + soff;
        const int8_t* u_ = Bu + (size_t)kk * 16384 + soff;
#pragma unroll
        for (int q = 0; q < 4; ++q) {
            async16(a  + q * 4096, lA_w  + q * 4096);
            async16(g_ + q * 4096, lBg_w + q * 4096);
            async16(u_ + q * 4096, lBu_w + q * 4096);
        }
        __syncthreads();

#pragma unroll
        for (int s = 0; s < 2; ++s) {
            const int sb = s * 8192;
            v4i af[4], bgf[4], buf2[4];
#pragma unroll
            for (int mt = 0; mt < 4; ++mt)
                af[mt] = *(const v4i*)(lA + sb + ((wm * 4 + mt) * 64 + lane) * 16);
#pragma unroll
            for (int nt = 0; nt < 4; ++nt) {
                bgf[nt]  = *(const v4i*)(lBg + sb + ((wn * 4 + nt) * 64 + lane) * 16);
                buf2[nt] = *(const v4i*)(lBu + sb + ((wn * 4 + nt) * 64 + lane) * 16);
            }
#pragma unroll
            for (int mt = 0; mt < 4; ++mt)
#pragma unroll
                for (int nt = 0; nt < 4; ++nt) {
                    accg[mt][nt] = __builtin_amdgcn_mfma_i32_16x16x64_i8(
                        af[mt], bgf[nt], accg[mt][nt], 0, 0, 0);
                    accu[mt][nt] = __builtin_amdgcn_mfma_i32_16x16x64_i8(
                        af[mt], buf2[nt], accu[mt][nt], 0, 0, 0);
                }
        }
    }

    // Epilogue: dequant, silu(gate)*up, requant -> qh in packed-A layout.
    const float sg = asg_p[0];
    const float sd = asd_p[0];
    const int jc = lane & 15, lg = lane >> 4;
    const size_t tile_base =
        ((size_t)bm * (I_DIM / 64) + (size_t)bn * 2 + wn) * 8192;
#pragma unroll
    for (int nt = 0; nt < 4; ++nt) {
        const int col = bn * 128 + wn * 64 + nt * 16 + jc;
        const float wsg = sg * ws_gate[col];
        const float wsu = sg * ws_up[col];
        const float bgv = b_gate[col];
        const float buv = b_up[col];
#pragma unroll
        for (int mt = 0; mt < 4; ++mt) {
            const size_t base = tile_base
                + (size_t)((((wm * 4 + mt) * 64) + nt * 16 + lg * 4) * 16 + jc);
#pragma unroll
            for (int r = 0; r < 4; ++r) {
                const float gate = (float)accg[mt][nt][r] * wsg + bgv;
                const float up   = (float)accu[mt][nt][r] * wsu + buv;
                const float hv = (gate / (1.0f + expf(-gate))) * up;
                const float qv = fminf(fmaxf(rintf(hv / sd), -127.f), 127.f);
                qh[base + (size_t)r * 16] = (int8_t)qv;
            }
        }
    }
}

// ---------------- down GEMM + dequant ----------------
// grid: 1D, (H/128)*(T/128) = 32*64 = 2048 blocks, 256 threads.
__global__ __launch_bounds__(256, 2)
void down_gemm(const int8_t* __restrict__ qh,
               const int8_t* __restrict__ wd8,
               const float* __restrict__ ws_down,
               const float* __restrict__ b_down,
               const float* __restrict__ asd_p,
               float* __restrict__ out) {
    __shared__ __align__(16) int8_t lA[16384];
    __shared__ __align__(16) int8_t lB[16384];

    const int tid = threadIdx.x;
    const int lane = tid & 63;
    const int w = tid >> 6;
    const int wm = w >> 1, wn = w & 1;

    int bm, bn;
    remap_tile(blockIdx.x, (H_DIM / 128) * (T_DIM / 128), H_DIM / 128, bm, bn);

    const int8_t* At = qh  + (size_t)bm * (I_DIM / 64) * 8192;
    const int8_t* Bt = wd8 + (size_t)bn * (I_DIM / 64) * 8192;

    v4i acc[4][4] = {};

    const int soff = (w * 64 + lane) * 16;
    int8_t* lA_w = lA + w * 1024;
    int8_t* lB_w = lB + w * 1024;

    for (int kk = 0; kk < I_DIM / 128; ++kk) {   // 86 steps
        __syncthreads();
        const int8_t* a = At + (size_t)kk * 16384 + soff;
        const int8_t* b = Bt + (size_t)kk * 16384 + soff;
#pragma unroll
        for (int q = 0; q < 4; ++q) {
            async16(a + q * 4096, lA_w + q * 4096);
            async16(b + q * 4096, lB_w + q * 4096);
        }
        __syncthreads();

#pragma unroll
        for (int s = 0; s < 2; ++s) {
            const int sb = s * 8192;
            v4i af[4], bf[4];
#pragma unroll
            for (int mt = 0; mt < 4; ++mt)
                af[mt] = *(const v4i*)(lA + sb + ((wm * 4 + mt) * 64 + lane) * 16);
#pragma unroll
            for (int nt = 0; nt < 4; ++nt)
                bf[nt] = *(const v4i*)(lB + sb + ((wn * 4 + nt) * 64 + lane) * 16);
#pragma unroll
            for (int mt = 0; mt < 4; ++mt)
#pragma unroll
                for (int nt = 0; nt < 4; ++nt)
                    acc[mt][nt] = __builtin_amdgcn_mfma_i32_16x16x64_i8(
                        af[mt], bf[nt], acc[mt][nt], 0, 0, 0);
        }
    }

    const float sd = asd_p[0];
    const int jc = lane & 15, lg = lane >> 4;
#pragma unroll
    for (int nt = 0; nt < 4; ++nt) {
        const int hcol = bn * 128 + wn * 64 + nt * 16 + jc;
        const float sc = sd * ws_down[hcol];
        const float bv = b_down[hcol];
#pragma unroll
        for (int mt = 0; mt < 4; ++mt) {
            const int trow0 = bm * 128 + wm * 64 + mt * 16 + lg * 4;
#pragma unroll
            for (int r = 0; r < 4; ++r)
                out[(size_t)(trow0 + r) * H_DIM + hcol] =
                    (float)acc[mt][nt][r] * sc + bv;
        }
    }
}

// ---------------- launch ----------------

extern "C" void kernel_launch(void* const* d_in, const int* in_sizes, int n_in,
                              void* d_out, int out_size, void* d_ws, size_t ws_size,
                              hipStream_t stream) {
    const float* x       = (const float*)d_in[0];
    const int*   w_gate  = (const int*)d_in[1];
    const int*   w_up    = (const int*)d_in[2];
    const int*   w_down  = (const int*)d_in[3];
    const float* ws_gate = (const float*)d_in[4];
    const float* ws_up   = (const float*)d_in[5];
    const float* ws_down = (const float*)d_in[6];
    const float* b_gate  = (const float*)d_in[7];
    const float* b_up    = (const float*)d_in[8];
    const float* b_down  = (const float*)d_in[9];
    const float* asg     = (const float*)d_in[10];
    const float* asd     = (const float*)d_in[11];
    float* out = (float*)d_out;

    int8_t* ws8 = (int8_t*)d_ws;
    int8_t* qx  = ws8;                       // 33,554,432 B
    int8_t* qh  = ws8 + 33554432;            // 90,177,536 B
    int8_t* wg8 = ws8 + 123731968;           // 45,088,768 B
    int8_t* wu8 = ws8 + 168820736;           // 45,088,768 B (end 213,909,504)
    int8_t* wd8 = wg8;                       // reused after gateup_gemm

    quant_pack_x<<<dim3(4096), dim3(256), 0, stream>>>(x, asg, qx);
    pack_w<<<dim3(5504), dim3(256), 0, stream>>>(w_gate, wg8, H_DIM);
    pack_w<<<dim3(5504), dim3(256), 0, stream>>>(w_up,   wu8, H_DIM);
    gateup_gemm<<<dim3(5504), dim3(256), 0, stream>>>(
        qx, wg8, wu8, ws_gate, ws_up, b_gate, b_up, asg, asd, qh);
    pack_w<<<dim3(5504), dim3(256), 0, stream>>>(w_down, wd8, I_DIM);
    down_gemm<<<dim3(2048), dim3(256), 0, stream>>>(
        qh, wd8, ws_down, b_down, asd, out);
}